// Round 7
// baseline (98.717 us; speedup 1.0000x reference)
//
#include <hip/hip_runtime.h>
#include <math.h>

#define D 256
#define N 16
#define R 16
#define MAGIC 0x5A17C0DEu

// ws float offsets. Tokens live after the three data regions (uint slots).
#define WS_X1C  0
#define WS_RES1 16384
#define WS_X2C  32768
#define WS_TOK  49152

__device__ __forceinline__ float silu_f(float x) { return x / (1.0f + expf(-x)); }
__device__ __forceinline__ float softplus_f(float x) {
    return fmaxf(x, 0.0f) + log1pf(expf(-fabsf(x)));
}

// ONE kernel, 4*batch blocks x 1024 threads. Blocks [0, 3*batch): producers
// (rmsnorm + one 256-dot region of the in_w matvec each); blocks [3*batch,
// 4*batch): consumers (conv/silu, xproj, dt/scan, out_w, final rmsnorm).
// Cross-block handoff via agent-scope atomics + MAGIC tokens (ws is poisoned
// 0xAA each launch, so poison != MAGIC guarantees a clean baseline).
// 4*64=256 blocks x 16 waves: all co-resident (<= 2 blocks/CU capacity), so
// the consumer spin cannot deadlock.
__global__ __launch_bounds__(1024) void k_mamba_pc(
    const float* __restrict__ x1_in, const float* __restrict__ x2_in,
    const float* __restrict__ norm_w, const float* __restrict__ conv_w,
    const float* __restrict__ conv_b, const float* __restrict__ in_w,
    const float* __restrict__ xproj_w, const float* __restrict__ dt_w,
    const float* __restrict__ dt_b, const float* __restrict__ out_w,
    const float* __restrict__ A_log, const float* __restrict__ Dp,
    const int* __restrict__ l_ptr, float* __restrict__ ws,
    float* __restrict__ out, int nbatch)
{
    __shared__ float s_n[D];
    __shared__ float s_red[4];
    __shared__ float s_x2s[4][D];
    __shared__ float s_xdbl[4][48];   // [tc][delta(16)|B(16)|C(16)]
    __shared__ float s_y[D];
    __shared__ float s_z[D];

    const int t   = threadIdx.x;
    const int q   = t & 3;
    const int dot = t >> 2;           // 0..255
    const int nprod = nbatch * 3;
    unsigned int* __restrict__ tok = (unsigned int*)(ws + WS_TOK);

    if ((int)blockIdx.x < nprod) {
        // ======================= producer =======================
        const int p = blockIdx.x;
        const int b = p / 3;
        const int c = p % 3;          // 0: x1c(rows 0-255,n1) 1: res1(rows 256-511,n1) 2: x2c(rows 0-255,n2)
        const int row = (c == 1) ? (D + dot) : dot;

        // prefetch weights immediately (overlaps the norm chain)
        const float* __restrict__ wr = in_w + (size_t)row * D;
        float4 w[16];
        #pragma unroll
        for (int k = 0; k < 16; ++k) w[k] = *(const float4*)(wr + q * 4 + 16 * k);

        // rmsnorm of the one input row this block needs
        const float* __restrict__ xrow = ((c == 2) ? x2_in : x1_in) + (size_t)b * D;
        float v = 0.0f;
        if (t < D) {
            v = xrow[t];
            float pp = v * v;
            #pragma unroll
            for (int off = 32; off >= 1; off >>= 1) pp += __shfl_down(pp, off, 64);
            if ((t & 63) == 0) s_red[t >> 6] = pp;
        }
        __syncthreads();
        if (t < D) {
            const float ss = s_red[0] + s_red[1] + s_red[2] + s_red[3];
            s_n[t] = v * rsqrtf(ss * (1.0f / D) + 1e-5f) * norm_w[t];
        }
        __syncthreads();

        // 256 dots, 4 threads/dot, interleaved quarters
        float acc = 0.0f;
        #pragma unroll
        for (int k = 0; k < 16; ++k) {
            const int e = q * 4 + 16 * k;
            const float4 n4 = *(const float4*)(s_n + e);
            acc += w[k].x*n4.x + w[k].y*n4.y + w[k].z*n4.z + w[k].w*n4.w;
        }
        acc += __shfl_xor(acc, 1, 64);
        acc += __shfl_xor(acc, 2, 64);
        if (q == 0) {
            const int off = (c == 0) ? WS_X1C : (c == 1) ? WS_RES1 : WS_X2C;
            // agent-scope store: visible at the device coherence point
            __hip_atomic_exchange(&ws[off + b * D + dot], acc,
                                  __ATOMIC_RELAXED, __HIP_MEMORY_SCOPE_AGENT);
        }
        __syncthreads();   // drains every thread's outstanding vmem ops
        if (t == 0)
            __hip_atomic_exchange(&tok[p], MAGIC,
                                  __ATOMIC_RELEASE, __HIP_MEMORY_SCOPE_AGENT);
        return;
    }

    // ======================= consumer =======================
    const int b = blockIdx.x - nprod;
    const int l = *l_ptr;

    // ---- entry prefetch: everything tid-addressable, overlaps producers ----
    const float* __restrict__ orow = out_w + (size_t)dot * D;
    float4 wo[8];
    #pragma unroll
    for (int k = 0; k < 8; ++k) wo[k] = *(const float4*)(orow + q * 4 + 16 * k);

    float cb = 0.0f, dtb = 0.0f, dpj = 0.0f, wnj = 0.0f;
    float4 cw = make_float4(0.f, 0.f, 0.f, 0.f);
    float dtr[R];
    float alog[N];
    if (t < D) {
        cw  = *(const float4*)(conv_w + 4 * t);
        cb  = conv_b[t];
        dtb = dt_b[t];
        dpj = Dp[t];
        wnj = norm_w[t];
        const float* __restrict__ dtrow = dt_w + (size_t)t * R;
        #pragma unroll
        for (int qq = 0; qq < R; ++qq) dtr[qq] = dtrow[qq];
        const float* __restrict__ arow = A_log + (size_t)t * N;
        #pragma unroll
        for (int n = 0; n < N; ++n) alog[n] = arow[n];
    }

    // ---- wait for this batch's 3 producers (bounded spin: fails visibly,
    //      never hangs) ----
    if (t == 0) {
        #pragma unroll
        for (int s = 0; s < 3; ++s) {
            int spin = 0;
            while (__hip_atomic_load(&tok[3 * b + s], __ATOMIC_ACQUIRE,
                                     __HIP_MEMORY_SCOPE_AGENT) != MAGIC &&
                   spin < (1 << 22)) {
                ++spin;
                __builtin_amdgcn_s_sleep(2);
            }
        }
    }
    __syncthreads();

    // ---- read handoff data (agent-scope loads bypass stale per-XCD L2) ----
    float x1c = 0.0f, x2c = 0.0f, res1 = 0.0f;
    if (t < D) {
        x1c  = __hip_atomic_load(&ws[WS_X1C  + b * D + t], __ATOMIC_RELAXED,
                                 __HIP_MEMORY_SCOPE_AGENT);
        x2c  = __hip_atomic_load(&ws[WS_X2C  + b * D + t], __ATOMIC_RELAXED,
                                 __HIP_MEMORY_SCOPE_AGENT);
        res1 = __hip_atomic_load(&ws[WS_RES1 + b * D + t], __ATOMIC_RELAXED,
                                 __HIP_MEMORY_SCOPE_AGENT);
    }

    // ---- phase A: conv + silu (threads 0..255) ----
    float x1s[4];
    if (t < D) {
        float ksum[4];
        ksum[0] = cw.w;
        ksum[1] = cw.z + cw.w;
        ksum[2] = cw.y + cw.z + cw.w;
        ksum[3] = cw.x + cw.y + cw.z + cw.w;
        #pragma unroll
        for (int tc = 0; tc < 4; ++tc) {
            x1s[tc] = silu_f(ksum[tc] * x1c + cb);
            s_x2s[tc][t] = silu_f(ksum[tc] * x2c + cb);
        }
    }
    __syncthreads();

    // ---- phase B: xproj, 192 dots x 4 threads (threads 0..767) ----
    if (t < 768) {
        const int tc = dot / 48;
        const int o  = dot % 48;
        const float* __restrict__ pr = xproj_w + (size_t)o * D;
        const float* __restrict__ xs = s_x2s[tc];
        float acc = 0.0f;
        #pragma unroll
        for (int k = 0; k < 16; ++k) {
            const int e = q * 4 + 16 * k;
            const float4 p4 = *(const float4*)(pr + e);
            const float4 x4 = *(const float4*)(xs + e);
            acc += p4.x*x4.x + p4.y*x4.y + p4.z*x4.z + p4.w*x4.w;
        }
        acc += __shfl_xor(acc, 1, 64);
        acc += __shfl_xor(acc, 2, 64);
        if (q == 0) s_xdbl[tc][o] = acc;
    }
    __syncthreads();

    // ---- phase C: delta, scan (closed-form tail), y (threads 0..255) ----
    if (t < D) {
        float delta[4];
        #pragma unroll
        for (int tc = 0; tc < 4; ++tc) {
            float acc = 0.0f;
            #pragma unroll
            for (int qq = 0; qq < R; ++qq) acc += s_xdbl[tc][qq] * dtr[qq];
            delta[tc] = softplus_f(acc + dtb);
        }
        float Aa[N];
        #pragma unroll
        for (int n = 0; n < N; ++n) Aa[n] = -expf(alog[n]);
        float h[N];
        #pragma unroll
        for (int n = 0; n < N; ++n) h[n] = 0.0f;
        const int nexp = (l < 3) ? l : 3;
        for (int tt = 0; tt < nexp; ++tt) {
            const float dl = delta[tt];
            const float du = dl * x1s[tt];
            #pragma unroll
            for (int n = 0; n < N; ++n) {
                const float dA = expf(dl * Aa[n]);
                h[n] = dA * h[n] + du * s_xdbl[tt][16 + n];
            }
        }
        if (l > 3) {
            const float dl = delta[3];
            const float du = dl * x1s[3];
            const float steps = (float)(l - 3);
            #pragma unroll
            for (int n = 0; n < N; ++n) {
                const float z   = dl * Aa[n];      // z < 0
                const float em1 = expm1f(z);
                const float emN = expm1f(steps * z);
                const float ratio = (em1 != 0.0f) ? (emN / em1) : steps;
                const float pw = emN + 1.0f;       // dA^steps
                h[n] = pw * h[n] + du * s_xdbl[3][16 + n] * ratio;
            }
        }
        const int fc = ((l - 1) < 3) ? (l - 1) : 3;
        float y = 0.0f;
        #pragma unroll
        for (int n = 0; n < N; ++n) y += h[n] * s_xdbl[fc][32 + n];
        y += x1s[fc] * dpj;
        y *= silu_f(res1);
        s_y[t] = y;
    }
    __syncthreads();

    // ---- phase D: out_w matvec, 256 dots x 4 threads (all 1024) ----
    {
        float4 wo2[8];
        #pragma unroll
        for (int k = 0; k < 8; ++k)
            wo2[k] = *(const float4*)(orow + q * 4 + 16 * (8 + k));
        float acc = 0.0f;
        #pragma unroll
        for (int k = 0; k < 8; ++k) {
            const int e = q * 4 + 16 * k;
            const float4 y4 = *(const float4*)(s_y + e);
            acc += wo[k].x*y4.x + wo[k].y*y4.y + wo[k].z*y4.z + wo[k].w*y4.w;
        }
        #pragma unroll
        for (int k = 0; k < 8; ++k) {
            const int e = q * 4 + 16 * (8 + k);
            const float4 y4 = *(const float4*)(s_y + e);
            acc += wo2[k].x*y4.x + wo2[k].y*y4.y + wo2[k].z*y4.z + wo2[k].w*y4.w;
        }
        acc += __shfl_xor(acc, 1, 64);
        acc += __shfl_xor(acc, 2, 64);
        if (q == 0) s_z[dot] = acc;
    }
    __syncthreads();

    // ---- phase E: final rmsnorm (threads 0..255) ----
    if (t < D) {
        const float zz = s_z[t];
        float p = zz * zz;
        #pragma unroll
        for (int off = 32; off >= 1; off >>= 1) p += __shfl_down(p, off, 64);
        if ((t & 63) == 0) s_red[t >> 6] = p;
    }
    __syncthreads();
    if (t < D) {
        const float ss = s_red[0] + s_red[1] + s_red[2] + s_red[3];
        out[b * D + t] = s_z[t] * rsqrtf(ss * (1.0f / D) + 1e-5f) * wnj;
    }
}

extern "C" void kernel_launch(void* const* d_in, const int* in_sizes, int n_in,
                              void* d_out, int out_size, void* d_ws, size_t ws_size,
                              hipStream_t stream) {
    const float* x1      = (const float*)d_in[0];
    const float* x2      = (const float*)d_in[1];
    const float* norm_w  = (const float*)d_in[2];
    const float* conv_w  = (const float*)d_in[3];
    const float* conv_b  = (const float*)d_in[4];
    const float* in_w    = (const float*)d_in[5];
    const float* xproj_w = (const float*)d_in[6];
    const float* dt_w    = (const float*)d_in[7];
    const float* dt_b    = (const float*)d_in[8];
    const float* out_w   = (const float*)d_in[9];
    const float* A_log   = (const float*)d_in[10];
    const float* Dp      = (const float*)d_in[11];
    const int*   l_ptr   = (const int*)d_in[12];
    float* out = (float*)d_out;
    float* ws  = (float*)d_ws;

    const int batch = in_sizes[0] / D;   // 64

    k_mamba_pc<<<dim3(batch * 4), dim3(1024), 0, stream>>>(
        x1, x2, norm_w, conv_w, conv_b, in_w, xproj_w, dt_w, dt_b,
        out_w, A_log, Dp, l_ptr, ws, out, batch);
}

// Round 8
// 92.978 us; speedup vs baseline: 1.0617x; 1.0617x over previous
//
#include <hip/hip_runtime.h>
#include <math.h>

#define D 256
#define N 16
#define R 16

// ws float offsets: x1c[64*256] | res1[64*256] | xdbl[64*192]
#define WS_X1C  0
#define WS_RES1 16384
#define WS_XDBL 32768

__device__ __forceinline__ float silu_f(float x) { return x / (1.0f + expf(-x)); }
__device__ __forceinline__ float softplus_f(float x) {
    return fmaxf(x, 0.0f) + log1pf(expf(-fabsf(x)));
}

// ---------------- K1: rmsnorm + in_w matvec (+ conv/xproj on c=2) --------
// grid: 3 blocks/batch x 1024 threads. c=0: x1c rows 0..255 (n1) -> ws.
// c=1: res1 rows 256..511 (n1) -> ws. c=2: x2c rows 0..255 (n2) -> LDS,
// then conv+silu -> xproj -> xdbl(192) -> ws. Weight prefetch at entry
// overlaps the rmsnorm chain.
__global__ __launch_bounds__(1024) void k1_produce(
    const float* __restrict__ x1_in, const float* __restrict__ x2_in,
    const float* __restrict__ norm_w, const float* __restrict__ conv_w,
    const float* __restrict__ conv_b, const float* __restrict__ in_w,
    const float* __restrict__ xproj_w, float* __restrict__ ws)
{
    __shared__ float s_n[D];
    __shared__ float s_red[4];
    __shared__ float s_x2s[4][D];   // c=2 only
    const int t   = threadIdx.x;
    const int q   = t & 3;
    const int dot = t >> 2;          // 0..255
    const int b   = blockIdx.x / 3;
    const int c   = blockIdx.x % 3;
    const int row = (c == 1) ? (D + dot) : dot;

    // ---- entry prefetch: in_w row quarter (16 float4) ----
    const float* __restrict__ wr = in_w + (size_t)row * D;
    float4 w[16];
    #pragma unroll
    for (int k = 0; k < 16; ++k) w[k] = *(const float4*)(wr + q * 4 + 16 * k);

    // conv row for c=2 (overlaps too)
    float4 cw = make_float4(0.f, 0.f, 0.f, 0.f);
    float cb = 0.0f;
    if (c == 2 && t < D) { cw = *(const float4*)(conv_w + 4 * t); cb = conv_b[t]; }

    // ---- rmsnorm of the one input row this block needs ----
    const float* __restrict__ xrow = ((c == 2) ? x2_in : x1_in) + (size_t)b * D;
    float v = 0.0f;
    if (t < D) {
        v = xrow[t];
        float pp = v * v;
        #pragma unroll
        for (int off = 32; off >= 1; off >>= 1) pp += __shfl_down(pp, off, 64);
        if ((t & 63) == 0) s_red[t >> 6] = pp;
    }
    __syncthreads();
    if (t < D) {
        const float ss = s_red[0] + s_red[1] + s_red[2] + s_red[3];
        s_n[t] = v * rsqrtf(ss * (1.0f / D) + 1e-5f) * norm_w[t];
    }
    __syncthreads();

    // ---- 256 dots, 4 threads/dot ----
    float acc = 0.0f;
    #pragma unroll
    for (int k = 0; k < 16; ++k) {
        const int e = q * 4 + 16 * k;
        const float4 n4 = *(const float4*)(s_n + e);
        acc += w[k].x*n4.x + w[k].y*n4.y + w[k].z*n4.z + w[k].w*n4.w;
    }
    acc += __shfl_xor(acc, 1, 64);
    acc += __shfl_xor(acc, 2, 64);

    if (c == 0) {
        if (q == 0) ws[WS_X1C + b * D + dot] = acc;
        return;
    }
    if (c == 1) {
        if (q == 0) ws[WS_RES1 + b * D + dot] = acc;
        return;
    }

    // ================= c = 2: conv + silu + xproj =================
    if (q == 0) s_n[dot] = acc;      // reuse s_n as x2c store
    __syncthreads();
    if (t < D) {
        const float x2c = s_n[t];
        float ksum[4];
        ksum[0] = cw.w;
        ksum[1] = cw.z + cw.w;
        ksum[2] = cw.y + cw.z + cw.w;
        ksum[3] = cw.x + cw.y + cw.z + cw.w;
        #pragma unroll
        for (int tc = 0; tc < 4; ++tc)
            s_x2s[tc][t] = silu_f(ksum[tc] * x2c + cb);
    }
    __syncthreads();

    // xproj: 192 dots x 4 threads (threads 0..767) -> ws
    if (t < 768) {
        const int tc = dot / 48;
        const int o  = dot % 48;
        const float* __restrict__ pr = xproj_w + (size_t)o * D;
        const float* __restrict__ xs = s_x2s[tc];
        float a2 = 0.0f;
        #pragma unroll
        for (int k = 0; k < 16; ++k) {
            const int e = q * 4 + 16 * k;
            const float4 p4 = *(const float4*)(pr + e);
            const float4 x4 = *(const float4*)(xs + e);
            a2 += p4.x*x4.x + p4.y*x4.y + p4.z*x4.z + p4.w*x4.w;
        }
        a2 += __shfl_xor(a2, 1, 64);
        a2 += __shfl_xor(a2, 2, 64);
        if (q == 0) ws[WS_XDBL + b * 192 + tc * 48 + o] = a2;
    }
}

// ---------------- K2: x1s, dt/scan/y, out_w, final rmsnorm ----------------
// grid: 64 blocks x 1024 threads. Everything tid-addressable prefetched at
// entry; single drain at the first barrier; only out_w's second half loads
// after that.
__global__ __launch_bounds__(1024) void k2_consume(
    const float* __restrict__ conv_w, const float* __restrict__ conv_b,
    const float* __restrict__ dt_w, const float* __restrict__ dt_b,
    const float* __restrict__ A_log, const float* __restrict__ Dp,
    const int* __restrict__ l_ptr, const float* __restrict__ out_w,
    const float* __restrict__ norm_w, const float* __restrict__ ws,
    float* __restrict__ out)
{
    __shared__ float s_xdbl[192];    // [tc*48 + (delta0..15|B0..15|C0..15)]
    __shared__ float s_y[D];
    __shared__ float s_z[D];
    __shared__ float s_red[4];
    const int b = blockIdx.x;
    const int t = threadIdx.x;
    const int q   = t & 3;
    const int dot = t >> 2;
    const int l = *l_ptr;

    // ---- entry prefetch ----
    const float* __restrict__ orow = out_w + (size_t)dot * D;
    float4 wo[8];
    #pragma unroll
    for (int k = 0; k < 8; ++k) wo[k] = *(const float4*)(orow + q * 4 + 16 * k);

    float xd = 0.0f;
    if (t < 192) xd = ws[WS_XDBL + b * 192 + t];

    float x1c = 0.0f, res1 = 0.0f, cb = 0.0f, dtb = 0.0f, dpj = 0.0f,
          wnj = 0.0f;
    float4 cw = make_float4(0.f, 0.f, 0.f, 0.f);
    float dtr[R];
    float alog[N];
    if (t < D) {
        x1c  = ws[WS_X1C  + b * D + t];
        res1 = ws[WS_RES1 + b * D + t];
        cw   = *(const float4*)(conv_w + 4 * t);
        cb   = conv_b[t];
        dtb  = dt_b[t];
        dpj  = Dp[t];
        wnj  = norm_w[t];
        const float* __restrict__ dtrow = dt_w + (size_t)t * R;
        #pragma unroll
        for (int qq = 0; qq < R; ++qq) dtr[qq] = dtrow[qq];
        const float* __restrict__ arow = A_log + (size_t)t * N;
        #pragma unroll
        for (int n = 0; n < N; ++n) alog[n] = arow[n];
    }
    if (t < 192) s_xdbl[t] = xd;
    __syncthreads();   // single drain point for all entry prefetches

    // ---- x1s, delta, scan (closed-form tail), y (threads 0..255) ----
    if (t < D) {
        float ksum[4];
        ksum[0] = cw.w;
        ksum[1] = cw.z + cw.w;
        ksum[2] = cw.y + cw.z + cw.w;
        ksum[3] = cw.x + cw.y + cw.z + cw.w;
        float x1s[4], delta[4];
        #pragma unroll
        for (int tc = 0; tc < 4; ++tc) {
            x1s[tc] = silu_f(ksum[tc] * x1c + cb);
            float acc = 0.0f;
            #pragma unroll
            for (int qq = 0; qq < R; ++qq) acc += s_xdbl[tc * 48 + qq] * dtr[qq];
            delta[tc] = softplus_f(acc + dtb);
        }
        float Aa[N];
        #pragma unroll
        for (int n = 0; n < N; ++n) Aa[n] = -expf(alog[n]);
        float h[N];
        #pragma unroll
        for (int n = 0; n < N; ++n) h[n] = 0.0f;
        const int nexp = (l < 3) ? l : 3;
        for (int tt = 0; tt < nexp; ++tt) {
            const float dl = delta[tt];
            const float du = dl * x1s[tt];
            #pragma unroll
            for (int n = 0; n < N; ++n) {
                const float dA = expf(dl * Aa[n]);
                h[n] = dA * h[n] + du * s_xdbl[tt * 48 + 16 + n];
            }
        }
        if (l > 3) {
            const float dl = delta[3];
            const float du = dl * x1s[3];
            const float steps = (float)(l - 3);
            #pragma unroll
            for (int n = 0; n < N; ++n) {
                const float z   = dl * Aa[n];      // z < 0
                const float em1 = expm1f(z);
                const float emN = expm1f(steps * z);
                const float ratio = (em1 != 0.0f) ? (emN / em1) : steps;
                const float pw = emN + 1.0f;       // dA^steps
                h[n] = pw * h[n] + du * s_xdbl[3 * 48 + 16 + n] * ratio;
            }
        }
        const int fc = ((l - 1) < 3) ? (l - 1) : 3;
        float y = 0.0f;
        #pragma unroll
        for (int n = 0; n < N; ++n) y += h[n] * s_xdbl[fc * 48 + 32 + n];
        y += x1s[fc] * dpj;
        y *= silu_f(res1);
        s_y[t] = y;
    }
    __syncthreads();

    // ---- out_w matvec, 256 dots x 4 threads (all 1024) ----
    {
        float4 wo2[8];
        #pragma unroll
        for (int k = 0; k < 8; ++k)
            wo2[k] = *(const float4*)(orow + q * 4 + 16 * (8 + k));
        float acc = 0.0f;
        #pragma unroll
        for (int k = 0; k < 8; ++k) {
            const int e = q * 4 + 16 * k;
            const float4 y4 = *(const float4*)(s_y + e);
            acc += wo[k].x*y4.x + wo[k].y*y4.y + wo[k].z*y4.z + wo[k].w*y4.w;
        }
        #pragma unroll
        for (int k = 0; k < 8; ++k) {
            const int e = q * 4 + 16 * (8 + k);
            const float4 y4 = *(const float4*)(s_y + e);
            acc += wo2[k].x*y4.x + wo2[k].y*y4.y + wo2[k].z*y4.z + wo2[k].w*y4.w;
        }
        acc += __shfl_xor(acc, 1, 64);
        acc += __shfl_xor(acc, 2, 64);
        if (q == 0) s_z[dot] = acc;
    }
    __syncthreads();

    // ---- final rmsnorm (threads 0..255) ----
    if (t < D) {
        const float zz = s_z[t];
        float p = zz * zz;
        #pragma unroll
        for (int off = 32; off >= 1; off >>= 1) p += __shfl_down(p, off, 64);
        if ((t & 63) == 0) s_red[t >> 6] = p;
    }
    __syncthreads();
    if (t < D) {
        const float ss = s_red[0] + s_red[1] + s_red[2] + s_red[3];
        out[b * D + t] = s_z[t] * rsqrtf(ss * (1.0f / D) + 1e-5f) * wnj;
    }
}

extern "C" void kernel_launch(void* const* d_in, const int* in_sizes, int n_in,
                              void* d_out, int out_size, void* d_ws, size_t ws_size,
                              hipStream_t stream) {
    const float* x1      = (const float*)d_in[0];
    const float* x2      = (const float*)d_in[1];
    const float* norm_w  = (const float*)d_in[2];
    const float* conv_w  = (const float*)d_in[3];
    const float* conv_b  = (const float*)d_in[4];
    const float* in_w    = (const float*)d_in[5];
    const float* xproj_w = (const float*)d_in[6];
    const float* dt_w    = (const float*)d_in[7];
    const float* dt_b    = (const float*)d_in[8];
    const float* out_w   = (const float*)d_in[9];
    const float* A_log   = (const float*)d_in[10];
    const float* Dp      = (const float*)d_in[11];
    const int*   l_ptr   = (const int*)d_in[12];
    float* out = (float*)d_out;
    float* ws  = (float*)d_ws;

    const int batch = in_sizes[0] / D;   // 64

    k1_produce<<<dim3(batch * 3), dim3(1024), 0, stream>>>(
        x1, x2, norm_w, conv_w, conv_b, in_w, xproj_w, ws);
    k2_consume<<<dim3(batch), dim3(1024), 0, stream>>>(
        conv_w, conv_b, dt_w, dt_b, A_log, Dp, l_ptr, out_w, norm_w, ws, out);
}

// Round 9
// 92.301 us; speedup vs baseline: 1.0695x; 1.0073x over previous
//
#include <hip/hip_runtime.h>
#include <math.h>

#define D 256
#define N 16
#define R 16

// ws float offsets: x1c | res1 | x2c (192 KB used)
#define WS_X1C  0
#define WS_RES1 16384
#define WS_X2C  32768

__device__ __forceinline__ float silu_f(float x) { return x / (1.0f + expf(-x)); }
__device__ __forceinline__ float softplus_f(float x) {
    return fmaxf(x, 0.0f) + log1pf(expf(-fabsf(x)));
}

// ---------------- K1: balanced rmsnorm + in_w matvec ----------------
// 4 blocks/batch x 1024 threads = 256 blocks (exactly 1/CU). 128 rows/block,
// 8 threads/row. cc=0: rows 0..127   -> x1c & x2c (one weight load, two dots)
//                cc=1: rows 128..255 -> x1c & x2c
//                cc=2: rows 256..383 -> res1[0..127]
//                cc=3: rows 384..511 -> res1[128..255]
__global__ __launch_bounds__(1024) void k1_inw(
    const float* __restrict__ x1_in, const float* __restrict__ x2_in,
    const float* __restrict__ norm_w, const float* __restrict__ in_w,
    float* __restrict__ ws)
{
    __shared__ float s_n1[D];
    __shared__ float s_n2[D];
    __shared__ float s_red[8];
    const int t  = threadIdx.x;
    const int b  = blockIdx.x >> 2;
    const int cc = blockIdx.x & 3;
    const int q8 = t & 7;
    const int r8 = t >> 3;            // 0..127
    const int row = cc * 128 + r8;
    const bool dual = (cc < 2);       // block-uniform

    // entry prefetch: 8 float4 of this thread's row-eighth (overlaps norm)
    const float* __restrict__ wr = in_w + (size_t)row * D;
    float4 w[8];
    #pragma unroll
    for (int k = 0; k < 8; ++k) w[k] = *(const float4*)(wr + 4 * q8 + 32 * k);

    // rmsnorm: n1 always, n2 only in dual blocks
    float v1 = 0.0f, v2 = 0.0f;
    if (t < D) {
        v1 = x1_in[b * D + t];
        float p1 = v1 * v1, p2 = 0.0f;
        if (dual) { v2 = x2_in[b * D + t]; p2 = v2 * v2; }
        #pragma unroll
        for (int off = 32; off >= 1; off >>= 1) {
            p1 += __shfl_down(p1, off, 64);
            p2 += __shfl_down(p2, off, 64);
        }
        if ((t & 63) == 0) { s_red[t >> 6] = p1; s_red[4 + (t >> 6)] = p2; }
    }
    __syncthreads();
    if (t < D) {
        const float ss1 = s_red[0] + s_red[1] + s_red[2] + s_red[3];
        const float wn = norm_w[t];
        s_n1[t] = v1 * rsqrtf(ss1 * (1.0f / D) + 1e-5f) * wn;
        if (dual) {
            const float ss2 = s_red[4] + s_red[5] + s_red[6] + s_red[7];
            s_n2[t] = v2 * rsqrtf(ss2 * (1.0f / D) + 1e-5f) * wn;
        }
    }
    __syncthreads();

    // dots: 8 threads/row, interleaved eighths (bank-conflict-free)
    float a1 = 0.0f, a2 = 0.0f;
    #pragma unroll
    for (int k = 0; k < 8; ++k) {
        const int e = 4 * q8 + 32 * k;
        const float4 n4 = *(const float4*)(s_n1 + e);
        a1 += w[k].x*n4.x + w[k].y*n4.y + w[k].z*n4.z + w[k].w*n4.w;
        if (dual) {
            const float4 m4 = *(const float4*)(s_n2 + e);
            a2 += w[k].x*m4.x + w[k].y*m4.y + w[k].z*m4.z + w[k].w*m4.w;
        }
    }
    a1 += __shfl_xor(a1, 1, 64); a1 += __shfl_xor(a1, 2, 64); a1 += __shfl_xor(a1, 4, 64);
    if (dual) {
        a2 += __shfl_xor(a2, 1, 64); a2 += __shfl_xor(a2, 2, 64); a2 += __shfl_xor(a2, 4, 64);
    }
    if (q8 == 0) {
        if (dual) {
            ws[WS_X1C + b * D + row] = a1;
            ws[WS_X2C + b * D + row] = a2;
        } else {
            ws[WS_RES1 + b * D + (row - 256)] = a1;
        }
    }
}

// ---------------- K2: conv+silu, xproj, dt/scan/y, out_w, rmsnorm ---------
// 64 blocks x 1024 threads. Entry prefetch: ws scalars, conv/dt/A_log rows,
// xproj segment (redundancy-free: 16 thr/row x 48 rows, one load serves all
// 4 time-classes), out_w first half. One drain at the first barrier; only
// out_w's second half loads after it.
__global__ __launch_bounds__(1024) void k2_rest(
    const float* __restrict__ conv_w, const float* __restrict__ conv_b,
    const float* __restrict__ xproj_w, const float* __restrict__ dt_w,
    const float* __restrict__ dt_b, const float* __restrict__ A_log,
    const float* __restrict__ Dp, const int* __restrict__ l_ptr,
    const float* __restrict__ out_w, const float* __restrict__ norm_w,
    const float* __restrict__ ws, float* __restrict__ out)
{
    __shared__ float s_x2s[4][D];
    __shared__ float s_xdbl[192];    // [tc*48 + (delta16|B16|C16)]
    __shared__ float s_y[D];
    __shared__ float s_z[D];
    __shared__ float s_red[4];
    const int b = blockIdx.x;
    const int t = threadIdx.x;
    const int q   = t & 3;
    const int dot = t >> 2;          // 0..255
    const int l = *l_ptr;

    // ---- entry prefetch, critical ws loads first ----
    float x1c = 0.0f, x2c = 0.0f, res1 = 0.0f, cb = 0.0f, dtb = 0.0f,
          dpj = 0.0f, wnj = 0.0f;
    float4 cw = make_float4(0.f, 0.f, 0.f, 0.f);
    float dtr[R];
    float alog[N];
    if (t < D) {
        x1c  = ws[WS_X1C  + b * D + t];
        x2c  = ws[WS_X2C  + b * D + t];
        res1 = ws[WS_RES1 + b * D + t];
        cw   = *(const float4*)(conv_w + 4 * t);
        cb   = conv_b[t];
        dtb  = dt_b[t];
        dpj  = Dp[t];
        wnj  = norm_w[t];
        const float* __restrict__ dtrow = dt_w + (size_t)t * R;
        #pragma unroll
        for (int qq = 0; qq < R; ++qq) dtr[qq] = dtrow[qq];
        const float* __restrict__ arow = A_log + (size_t)t * N;
        #pragma unroll
        for (int n = 0; n < N; ++n) alog[n] = arow[n];
    }
    // xproj segment: row o = t>>4 (0..47), segment s = t&15, 4 float4 each
    const int xo = t >> 4;
    const int xs = t & 15;
    float4 wx[4];
    if (t < 768) {
        const float* __restrict__ pr = xproj_w + (size_t)xo * D;
        #pragma unroll
        for (int k = 0; k < 4; ++k) wx[k] = *(const float4*)(pr + 4 * xs + 64 * k);
    }
    // out_w first half
    const float* __restrict__ orow = out_w + (size_t)dot * D;
    float4 wo[8];
    #pragma unroll
    for (int k = 0; k < 8; ++k) wo[k] = *(const float4*)(orow + q * 4 + 16 * k);

    // ---- phase A: conv + silu (threads 0..255) ----
    float x1s[4];
    if (t < D) {
        float ksum[4];
        ksum[0] = cw.w;
        ksum[1] = cw.z + cw.w;
        ksum[2] = cw.y + cw.z + cw.w;
        ksum[3] = cw.x + cw.y + cw.z + cw.w;
        #pragma unroll
        for (int tc = 0; tc < 4; ++tc) {
            x1s[tc] = silu_f(ksum[tc] * x1c + cb);
            s_x2s[tc][t] = silu_f(ksum[tc] * x2c + cb);
        }
    }
    __syncthreads();   // drains all entry prefetches once

    // ---- phase B: xproj, redundancy-free (threads 0..767) ----
    if (t < 768) {
        float acc[4] = {0.f, 0.f, 0.f, 0.f};
        #pragma unroll
        for (int k = 0; k < 4; ++k) {
            const int e = 4 * xs + 64 * k;
            #pragma unroll
            for (int tc = 0; tc < 4; ++tc) {
                const float4 x4 = *(const float4*)(&s_x2s[tc][e]);
                acc[tc] += wx[k].x*x4.x + wx[k].y*x4.y + wx[k].z*x4.z + wx[k].w*x4.w;
            }
        }
        #pragma unroll
        for (int tc = 0; tc < 4; ++tc) {
            acc[tc] += __shfl_xor(acc[tc], 1, 64);
            acc[tc] += __shfl_xor(acc[tc], 2, 64);
            acc[tc] += __shfl_xor(acc[tc], 4, 64);
            acc[tc] += __shfl_xor(acc[tc], 8, 64);
        }
        if (xs == 0) {
            #pragma unroll
            for (int tc = 0; tc < 4; ++tc) s_xdbl[tc * 48 + xo] = acc[tc];
        }
    }
    __syncthreads();

    // ---- phase C: delta, scan (closed-form tail), y (threads 0..255) ----
    if (t < D) {
        float delta[4];
        #pragma unroll
        for (int tc = 0; tc < 4; ++tc) {
            float acc = 0.0f;
            #pragma unroll
            for (int qq = 0; qq < R; ++qq) acc += s_xdbl[tc * 48 + qq] * dtr[qq];
            delta[tc] = softplus_f(acc + dtb);
        }
        float Aa[N];
        #pragma unroll
        for (int n = 0; n < N; ++n) Aa[n] = -expf(alog[n]);
        float h[N];
        #pragma unroll
        for (int n = 0; n < N; ++n) h[n] = 0.0f;
        const int nexp = (l < 3) ? l : 3;
        for (int tt = 0; tt < nexp; ++tt) {
            const float dl = delta[tt];
            const float du = dl * x1s[tt];
            #pragma unroll
            for (int n = 0; n < N; ++n) {
                const float dA = expf(dl * Aa[n]);
                h[n] = dA * h[n] + du * s_xdbl[tt * 48 + 16 + n];
            }
        }
        if (l > 3) {
            const float dl = delta[3];
            const float du = dl * x1s[3];
            const float steps = (float)(l - 3);
            #pragma unroll
            for (int n = 0; n < N; ++n) {
                const float z   = dl * Aa[n];      // z < 0
                const float em1 = expm1f(z);
                const float emN = expm1f(steps * z);
                const float ratio = (em1 != 0.0f) ? (emN / em1) : steps;
                const float pw = emN + 1.0f;       // dA^steps
                h[n] = pw * h[n] + du * s_xdbl[3 * 48 + 16 + n] * ratio;
            }
        }
        const int fc = ((l - 1) < 3) ? (l - 1) : 3;
        float y = 0.0f;
        #pragma unroll
        for (int n = 0; n < N; ++n) y += h[n] * s_xdbl[fc * 48 + 32 + n];
        y += x1s[fc] * dpj;
        y *= silu_f(res1);
        s_y[t] = y;
    }
    __syncthreads();

    // ---- phase D: out_w matvec, 256 dots x 4 threads (all 1024) ----
    {
        float4 wo2[8];
        #pragma unroll
        for (int k = 0; k < 8; ++k)
            wo2[k] = *(const float4*)(orow + q * 4 + 16 * (8 + k));
        float acc = 0.0f;
        #pragma unroll
        for (int k = 0; k < 8; ++k) {
            const int e = q * 4 + 16 * k;
            const float4 y4 = *(const float4*)(s_y + e);
            acc += wo[k].x*y4.x + wo[k].y*y4.y + wo[k].z*y4.z + wo[k].w*y4.w;
        }
        #pragma unroll
        for (int k = 0; k < 8; ++k) {
            const int e = q * 4 + 16 * (8 + k);
            const float4 y4 = *(const float4*)(s_y + e);
            acc += wo2[k].x*y4.x + wo2[k].y*y4.y + wo2[k].z*y4.z + wo2[k].w*y4.w;
        }
        acc += __shfl_xor(acc, 1, 64);
        acc += __shfl_xor(acc, 2, 64);
        if (q == 0) s_z[dot] = acc;
    }
    __syncthreads();

    // ---- phase E: final rmsnorm (threads 0..255) ----
    if (t < D) {
        const float zz = s_z[t];
        float p = zz * zz;
        #pragma unroll
        for (int off = 32; off >= 1; off >>= 1) p += __shfl_down(p, off, 64);
        if ((t & 63) == 0) s_red[t >> 6] = p;
    }
    __syncthreads();
    if (t < D) {
        const float ss = s_red[0] + s_red[1] + s_red[2] + s_red[3];
        out[b * D + t] = s_z[t] * rsqrtf(ss * (1.0f / D) + 1e-5f) * wnj;
    }
}

extern "C" void kernel_launch(void* const* d_in, const int* in_sizes, int n_in,
                              void* d_out, int out_size, void* d_ws, size_t ws_size,
                              hipStream_t stream) {
    const float* x1      = (const float*)d_in[0];
    const float* x2      = (const float*)d_in[1];
    const float* norm_w  = (const float*)d_in[2];
    const float* conv_w  = (const float*)d_in[3];
    const float* conv_b  = (const float*)d_in[4];
    const float* in_w    = (const float*)d_in[5];
    const float* xproj_w = (const float*)d_in[6];
    const float* dt_w    = (const float*)d_in[7];
    const float* dt_b    = (const float*)d_in[8];
    const float* out_w   = (const float*)d_in[9];
    const float* A_log   = (const float*)d_in[10];
    const float* Dp      = (const float*)d_in[11];
    const int*   l_ptr   = (const int*)d_in[12];
    float* out = (float*)d_out;
    float* ws  = (float*)d_ws;

    const int batch = in_sizes[0] / D;   // 64

    k1_inw<<<dim3(batch * 4), dim3(1024), 0, stream>>>(x1, x2, norm_w, in_w, ws);
    k2_rest<<<dim3(batch), dim3(1024), 0, stream>>>(conv_w, conv_b, xproj_w,
                                                    dt_w, dt_b, A_log, Dp, l_ptr,
                                                    out_w, norm_w, ws, out);
}